// Round 11
// baseline (106.830 us; speedup 1.0000x reference)
//
#include <hip/hip_runtime.h>
#include <hip/hip_bf16.h>

// ---------------------------------------------------------------------------
// MoE conv via combined-weight trick + bf16 MFMA. 3-kernel pipeline:
//   T transpose:    xt[b][h][g][w][ci8] (bf16) + gpart[b][h][ci]
//   C combine_gate: per-(cog,b) block derives gates from gpart (softmax/top4),
//                   emits wc[b][p][g][co][ci8] + bc[b][co]; extra block column
//                   computes aux loss concurrently.
//   D conv_mfma:    wc[b] (72 KB = 4608 x 16B) staged in LDS; 4 waves,
//                   wave = 64co x 64px (4x4 MFMA tiles).
// Notes: coop single-kernel fusion (r7/r8) regressed (VGPR spill + grid.sync
// stall). r10 NaN bug: staging loop must cover 4608 vectors -> 18 iters at
// 256 threads (9 was for 512 threads). Harness fixed cost ~87 us (r8 calib).
// ---------------------------------------------------------------------------

typedef __attribute__((ext_vector_type(8))) short bf16x8;
typedef __attribute__((ext_vector_type(4))) float f32x4;

__device__ inline unsigned short f2bf(float f) {
  unsigned u = __builtin_bit_cast(unsigned, f);
  unsigned r = u + 0x7FFFu + ((u >> 16) & 1u);
  return (unsigned short)(r >> 16);
}

// ---- Kernel T: xt[b][h][g][w][ci8] + gpart[b][h][ci] ----------------------
__global__ __launch_bounds__(256) void transpose_kernel(const float* __restrict__ x,
                                                        unsigned short* __restrict__ xt,
                                                        float* __restrict__ gpart) {
  int bh = blockIdx.x;  // b*64 + h
  int b = bh >> 6, h = bh & 63;
  __shared__ float tile[64][65];
  __shared__ float part[4][64];
  int t = threadIdx.x;
#pragma unroll
  for (int k = 0; k < 4; ++k) {
    int idx = t + k * 256;      // 0..1023
    int ci = idx >> 4;          // 0..63
    int w4 = idx & 15;          // 0..15
    float4 v = *(const float4*)(x + ((((size_t)b * 64 + ci) * 64 + h) * 64 + w4 * 4));
    tile[ci][w4 * 4 + 0] = v.x;
    tile[ci][w4 * 4 + 1] = v.y;
    tile[ci][w4 * 4 + 2] = v.z;
    tile[ci][w4 * 4 + 3] = v.w;
  }
  __syncthreads();
  {  // gate partial sums, fully parallel: thread (q,ci) sums 16 w's
    int ci = t & 63, q = t >> 6;
    float s = 0.f;
#pragma unroll
    for (int i = 0; i < 16; ++i) s += tile[ci][q * 16 + i];
    part[q][ci] = s;
  }
#pragma unroll
  for (int it = 0; it < 2; ++it) {
    int idx = t + it * 256;  // 0..511
    int g = idx >> 6;        // ci-group 0..7
    int wo = idx & 63;
    bf16x8 v;
#pragma unroll
    for (int j = 0; j < 8; ++j) v[j] = (short)f2bf(tile[g * 8 + j][wo]);
    *(bf16x8*)(xt + (((size_t)bh * 8 + g) * 64 + wo) * 8) = v;
  }
  __syncthreads();
  if (t < 64) gpart[(size_t)bh * 64 + t] = part[0][t] + part[1][t] + part[2][t] + part[3][t];
}

// ---- softmax + stable top-4 helper (single thread, 16 experts) ------------
__device__ inline void softmax_top4(const float* sl, float* gv, int* ge) {
  float m = sl[0];
#pragma unroll
  for (int i = 1; i < 16; ++i) m = fmaxf(m, sl[i]);
  float p[16];
  float z = 0.f;
#pragma unroll
  for (int i = 0; i < 16; ++i) { p[i] = expf(sl[i] - m); z += p[i]; }
#pragma unroll
  for (int i = 0; i < 16; ++i) p[i] /= z;
  bool used[16];
#pragma unroll
  for (int i = 0; i < 16; ++i) used[i] = false;
  float val[4];
  for (int j = 0; j < 4; ++j) {
    int bi = 0; float bv = -1.f;
    for (int i = 0; i < 16; ++i)
      if (!used[i] && p[i] > bv) { bv = p[i]; bi = i; }
    used[bi] = true; ge[j] = bi; val[j] = bv;
  }
  float ssum = val[0] + val[1] + val[2] + val[3] + 1e-6f;
  for (int j = 0; j < 4; ++j) gv[j] = val[j] / ssum;
}

// ---- Kernel C: fused gate + combine (+ loss in extra block column) --------
// grid (17, 16): cog 0..15 -> combine 4 co for batch b; cog==16,b==0 -> loss.
__global__ __launch_bounds__(256) void combine_gate_kernel(const float* __restrict__ gpart,
                                                           const float* __restrict__ w_gate,
                                                           const float* __restrict__ W,
                                                           const float* __restrict__ bias,
                                                           unsigned short* __restrict__ wc,
                                                           float* __restrict__ bc,
                                                           float* __restrict__ loss_out) {
  int cog = blockIdx.x;  // 0..16
  int b = blockIdx.y;
  int t = threadIdx.x;

  if (cog == 16) {  // ---- loss block (one per grid) ----
    if (b != 0) return;
    __shared__ float red[4][64];
    __shared__ float sgx[16][64];
    __shared__ float sl[16][16];
    __shared__ float sg[16][16];
    __shared__ float simp[16], sld[16];
    int hg = t >> 6, ci = t & 63;
    for (int bb = 0; bb < 16; ++bb) {
      float s = 0.f;
#pragma unroll
      for (int hh = 0; hh < 16; ++hh)
        s += gpart[((size_t)(bb * 64 + hg * 16 + hh)) * 64 + ci];
      red[hg][ci] = s;
      __syncthreads();
      if (t < 64) sgx[bb][t] = (red[0][t] + red[1][t] + red[2][t] + red[3][t]) * (1.0f / 4096.0f);
      __syncthreads();
    }
    {
      int bb = t >> 4, e = t & 15;
      float acc = 0.f;
      for (int c = 0; c < 64; ++c) acc += sgx[bb][c] * w_gate[c * 16 + e];
      sl[bb][e] = acc;
    }
    __syncthreads();
    if (t < 16) {
      float gv[4]; int ge[4];
      softmax_top4(sl[t], gv, ge);
#pragma unroll
      for (int i = 0; i < 16; ++i) sg[t][i] = 0.f;
      for (int j = 0; j < 4; ++j) sg[t][ge[j]] = gv[j];
    }
    __syncthreads();
    if (t < 16) {
      int ee = t; float imp = 0.f, ld = 0.f;
      for (int bb = 0; bb < 16; ++bb) {
        float g = sg[bb][ee];
        imp += g;
        if (g > 0.f) ld += 1.f;
      }
      simp[ee] = imp; sld[ee] = ld;
    }
    __syncthreads();
    if (t == 0) {
      float mi = 0.f, ml = 0.f;
      for (int i = 0; i < 16; ++i) { mi += simp[i]; ml += sld[i]; }
      mi *= (1.f / 16.f); ml *= (1.f / 16.f);
      float vi = 0.f, vl = 0.f;
      for (int i = 0; i < 16; ++i) {
        float d = simp[i] - mi; vi += d * d;
        float dl = sld[i] - ml; vl += dl * dl;
      }
      vi *= (1.f / 15.f); vl *= (1.f / 15.f);  // ddof=1
      loss_out[0] = (vi / (mi * mi + 1e-10f) + vl / (ml * ml + 1e-10f)) * 0.01f;
    }
    return;
  }

  // ---- combine block: derive this b's gates locally, then combine slab ----
  __shared__ float red[4][64];
  __shared__ float sgx[64];
  __shared__ float sl[16];
  __shared__ float g[4];
  __shared__ int e[4];
  __shared__ float was[2304];  // [co_l][ci][p] in W-native order
  {
    int hg = t >> 6, ci = t & 63;
    float s = 0.f;
#pragma unroll
    for (int hh = 0; hh < 16; ++hh)
      s += gpart[((size_t)(b * 64 + hg * 16 + hh)) * 64 + ci];
    red[hg][ci] = s;
  }
  __syncthreads();
  if (t < 64) sgx[t] = (red[0][t] + red[1][t] + red[2][t] + red[3][t]) * (1.0f / 4096.0f);
  __syncthreads();
  if (t < 16) {
    float acc = 0.f;
    for (int c = 0; c < 64; ++c) acc += sgx[c] * w_gate[c * 16 + t];
    sl[t] = acc;
  }
  __syncthreads();
  if (t == 0) {
    float gv[4]; int ge[4];
    softmax_top4(sl, gv, ge);
#pragma unroll
    for (int j = 0; j < 4; ++j) { g[j] = gv[j]; e[j] = ge[j]; }
  }
  __syncthreads();
  float g0 = g[0], g1 = g[1], g2 = g[2], g3 = g[3];
  int e0 = e[0], e1 = e[1], e2 = e[2], e3 = e[3];
  if (cog == 0 && t < 64)
    bc[b * 64 + t] = g0 * bias[e0 * 64 + t] + g1 * bias[e1 * 64 + t] +
                     g2 * bias[e2 * 64 + t] + g3 * bias[e3 * 64 + t];
  const float* b0 = W + e0 * 36864 + cog * 2304;
  const float* b1 = W + e1 * 36864 + cog * 2304;
  const float* b2 = W + e2 * 36864 + cog * 2304;
  const float* b3 = W + e3 * 36864 + cog * 2304;
  float acc[9];
#pragma unroll
  for (int j = 0; j < 9; ++j) {
    int o = t + j * 256;  // coalesced
    acc[j] = g0 * b0[o] + g1 * b1[o] + g2 * b2[o] + g3 * b3[o];
  }
#pragma unroll
  for (int j = 0; j < 9; ++j) was[t + j * 256] = acc[j];
  __syncthreads();
  for (int v = t; v < 288; v += 256) {
    int co_l = v & 3, gg = (v >> 2) & 7, p = v >> 5;
    bf16x8 ov;
#pragma unroll
    for (int j = 0; j < 8; ++j)
      ov[j] = (short)f2bf(was[co_l * 576 + (gg * 8 + j) * 9 + p]);
    *(bf16x8*)(wc + (size_t)b * 36864 + ((p * 8 + gg) * 64 + cog * 4 + co_l) * 8) = ov;
  }
}

// ---- Kernel D: conv via 9 shifted K=64 bf16 MFMA GEMMs --------------------
// grid (16 row-tiles, 16 b) = 256 blocks; 256 threads = 4 waves;
// wc[b] slab (72 KB = 4608 x 16B vectors) staged in LDS (18 iters x 256 thr);
// wave = row: 64co x 64px, 4x4 MFMA tiles.
__global__ __launch_bounds__(256, 2) void conv_mfma(const unsigned short* __restrict__ xt,
                                                    const unsigned short* __restrict__ wc,
                                                    const float* __restrict__ bc,
                                                    float* __restrict__ y) {
  __shared__ __align__(16) unsigned short wcs[36864];  // 72 KB
  int rt = blockIdx.x;  // 0..15
  int b = blockIdx.y;   // 0..15
  int tid = threadIdx.x;
  const unsigned short* wcb = wc + (size_t)b * 36864;
  // stage combined-weight slab: 4608 x 16B, coalesced, 18 per thread
#pragma unroll
  for (int i = 0; i < 18; ++i)
    ((bf16x8*)wcs)[tid + i * 256] = ((const bf16x8*)wcb)[tid + i * 256];
  __syncthreads();

  int wv = tid >> 6, L = tid & 63;
  int lane15 = L & 15, quad = L >> 4;
  int row = rt * 4 + wv;
  const unsigned short* xtb = xt + ((size_t)b << 18);  // 64h*8g*64w*8
  f32x4 acc[4][4];
#pragma unroll
  for (int mt = 0; mt < 4; ++mt)
#pragma unroll
    for (int nt = 0; nt < 4; ++nt) acc[mt][nt] = (f32x4){0.f, 0.f, 0.f, 0.f};
  const bf16x8 zero = {0, 0, 0, 0, 0, 0, 0, 0};
#pragma unroll
  for (int p = 0; p < 9; ++p) {
    int dr = p / 3, dc = p % 3;
    int h = row + dr - 1;
    bool hok = (unsigned)h < 64u;
#pragma unroll
    for (int ck = 0; ck < 2; ++ck) {
      int g = ck * 4 + quad;
      bf16x8 bfr[4];
#pragma unroll
      for (int nt = 0; nt < 4; ++nt) {
        int w = nt * 16 + lane15 + dc - 1;
        bf16x8 v = zero;
        if (hok && (unsigned)w < 64u)
          v = *(const bf16x8*)(xtb + (((h << 3) + g) << 9) + (w << 3));
        bfr[nt] = v;
      }
      bf16x8 afr[4];
#pragma unroll
      for (int mt = 0; mt < 4; ++mt)
        afr[mt] = *(const bf16x8*)(wcs + ((((p << 3) + g) << 6) + mt * 16 + lane15) * 8);
#pragma unroll
      for (int mt = 0; mt < 4; ++mt)
#pragma unroll
        for (int nt = 0; nt < 4; ++nt)
          acc[mt][nt] = __builtin_amdgcn_mfma_f32_16x16x32_bf16(afr[mt], bfr[nt], acc[mt][nt], 0, 0, 0);
    }
  }
#pragma unroll
  for (int mt = 0; mt < 4; ++mt) {
#pragma unroll
    for (int r = 0; r < 4; ++r) {
      int co = mt * 16 + quad * 4 + r;
      float bv = bc[(b << 6) + co];
#pragma unroll
      for (int nt = 0; nt < 4; ++nt) {
        int w = nt * 16 + lane15;
        y[(((size_t)(b << 6) + co) << 12) + (row << 6) + w] = acc[mt][nt][r] + bv;
      }
    }
  }
}

// ---------------------------------------------------------------------------
extern "C" void kernel_launch(void* const* d_in, const int* in_sizes, int n_in,
                              void* d_out, int out_size, void* d_ws, size_t ws_size,
                              hipStream_t stream) {
  const float* x = (const float*)d_in[0];       // (16,64,64,64)
  const float* w_gate = (const float*)d_in[1];  // (64,16)
  const float* W = (const float*)d_in[3];       // (16,64,64,3,3)
  const float* bias = (const float*)d_in[4];    // (16,64)
  float* out = (float*)d_out;                   // y (4194304) ++ loss (1)
  float* ws = (float*)d_ws;

  float* gpart = ws;                                     // [0, 65536) f
  float* bc = ws + 65536;                                // [65536, 66560) f
  unsigned short* wc = (unsigned short*)(ws + 66560);    // 589824 bf16
  unsigned short* xt = (unsigned short*)(ws + 361472);   // 4194304 bf16

  transpose_kernel<<<1024, 256, 0, stream>>>(x, xt, gpart);
  {
    dim3 grid(17, 16);
    combine_gate_kernel<<<grid, 256, 0, stream>>>(gpart, w_gate, W, bias, wc, bc,
                                                  out + 4194304);
  }
  {
    dim3 grid(16, 16);
    conv_mfma<<<grid, 256, 0, stream>>>(xt, wc, bc, out);
  }
}

// Round 12
// 103.384 us; speedup vs baseline: 1.0333x; 1.0333x over previous
//
#include <hip/hip_runtime.h>
#include <hip/hip_bf16.h>

// ---------------------------------------------------------------------------
// MoE conv via combined-weight trick + bf16 MFMA. 3-kernel pipeline (best
// measured configuration = r9):
//   T transpose:    xt[b][h][g][w][ci8] (bf16) + gpart[b][h][ci]
//   C combine_gate: per-(cog,b) block derives gates from gpart (softmax/top4),
//                   emits wc[b][p][g][co][ci8] + bc[b][co]; extra block column
//                   computes aux loss concurrently.
//   D conv_mfma:    512 thr / 8 waves; wc[b] (72 KB) staged in LDS; wave =
//                   64co x 32px (4x2 MFMA tiles).
// Measured design notes:
//   - 8 waves/CU beats 4 waves with bigger tiles (r11: 106.8 vs r9: 103.8):
//     conv is latency-hiding-bound, not LDS-BW-bound.
//   - coop single-kernel fusion regressed hard (r8: VGPR spill + grid.sync).
//   - harness fixed cost ~87 us (r8 calibration); our kernels ~17 us.
// ---------------------------------------------------------------------------

typedef __attribute__((ext_vector_type(8))) short bf16x8;
typedef __attribute__((ext_vector_type(4))) float f32x4;

__device__ inline unsigned short f2bf(float f) {
  unsigned u = __builtin_bit_cast(unsigned, f);
  unsigned r = u + 0x7FFFu + ((u >> 16) & 1u);
  return (unsigned short)(r >> 16);
}

// ---- Kernel T: xt[b][h][g][w][ci8] + gpart[b][h][ci] ----------------------
__global__ __launch_bounds__(256) void transpose_kernel(const float* __restrict__ x,
                                                        unsigned short* __restrict__ xt,
                                                        float* __restrict__ gpart) {
  int bh = blockIdx.x;  // b*64 + h
  int b = bh >> 6, h = bh & 63;
  __shared__ float tile[64][65];
  __shared__ float part[4][64];
  int t = threadIdx.x;
#pragma unroll
  for (int k = 0; k < 4; ++k) {
    int idx = t + k * 256;      // 0..1023
    int ci = idx >> 4;          // 0..63
    int w4 = idx & 15;          // 0..15
    float4 v = *(const float4*)(x + ((((size_t)b * 64 + ci) * 64 + h) * 64 + w4 * 4));
    tile[ci][w4 * 4 + 0] = v.x;
    tile[ci][w4 * 4 + 1] = v.y;
    tile[ci][w4 * 4 + 2] = v.z;
    tile[ci][w4 * 4 + 3] = v.w;
  }
  __syncthreads();
  {  // gate partial sums, fully parallel: thread (q,ci) sums 16 w's
    int ci = t & 63, q = t >> 6;
    float s = 0.f;
#pragma unroll
    for (int i = 0; i < 16; ++i) s += tile[ci][q * 16 + i];
    part[q][ci] = s;
  }
#pragma unroll
  for (int it = 0; it < 2; ++it) {
    int idx = t + it * 256;  // 0..511
    int g = idx >> 6;        // ci-group 0..7
    int wo = idx & 63;
    bf16x8 v;
#pragma unroll
    for (int j = 0; j < 8; ++j) v[j] = (short)f2bf(tile[g * 8 + j][wo]);
    *(bf16x8*)(xt + (((size_t)bh * 8 + g) * 64 + wo) * 8) = v;
  }
  __syncthreads();
  if (t < 64) gpart[(size_t)bh * 64 + t] = part[0][t] + part[1][t] + part[2][t] + part[3][t];
}

// ---- softmax + stable top-4 helper (single thread, 16 experts) ------------
__device__ inline void softmax_top4(const float* sl, float* gv, int* ge) {
  float m = sl[0];
#pragma unroll
  for (int i = 1; i < 16; ++i) m = fmaxf(m, sl[i]);
  float p[16];
  float z = 0.f;
#pragma unroll
  for (int i = 0; i < 16; ++i) { p[i] = expf(sl[i] - m); z += p[i]; }
#pragma unroll
  for (int i = 0; i < 16; ++i) p[i] /= z;
  bool used[16];
#pragma unroll
  for (int i = 0; i < 16; ++i) used[i] = false;
  float val[4];
  for (int j = 0; j < 4; ++j) {
    int bi = 0; float bv = -1.f;
    for (int i = 0; i < 16; ++i)
      if (!used[i] && p[i] > bv) { bv = p[i]; bi = i; }
    used[bi] = true; ge[j] = bi; val[j] = bv;
  }
  float ssum = val[0] + val[1] + val[2] + val[3] + 1e-6f;
  for (int j = 0; j < 4; ++j) gv[j] = val[j] / ssum;
}

// ---- Kernel C: fused gate + combine (+ loss in extra block column) --------
// grid (17, 16): cog 0..15 -> combine 4 co for batch b; cog==16,b==0 -> loss.
__global__ __launch_bounds__(256) void combine_gate_kernel(const float* __restrict__ gpart,
                                                           const float* __restrict__ w_gate,
                                                           const float* __restrict__ W,
                                                           const float* __restrict__ bias,
                                                           unsigned short* __restrict__ wc,
                                                           float* __restrict__ bc,
                                                           float* __restrict__ loss_out) {
  int cog = blockIdx.x;  // 0..16
  int b = blockIdx.y;
  int t = threadIdx.x;

  if (cog == 16) {  // ---- loss block (one per grid) ----
    if (b != 0) return;
    __shared__ float red[4][64];
    __shared__ float sgx[16][64];
    __shared__ float sl[16][16];
    __shared__ float sg[16][16];
    __shared__ float simp[16], sld[16];
    int hg = t >> 6, ci = t & 63;
    for (int bb = 0; bb < 16; ++bb) {
      float s = 0.f;
#pragma unroll
      for (int hh = 0; hh < 16; ++hh)
        s += gpart[((size_t)(bb * 64 + hg * 16 + hh)) * 64 + ci];
      red[hg][ci] = s;
      __syncthreads();
      if (t < 64) sgx[bb][t] = (red[0][t] + red[1][t] + red[2][t] + red[3][t]) * (1.0f / 4096.0f);
      __syncthreads();
    }
    {
      int bb = t >> 4, e = t & 15;
      float acc = 0.f;
      for (int c = 0; c < 64; ++c) acc += sgx[bb][c] * w_gate[c * 16 + e];
      sl[bb][e] = acc;
    }
    __syncthreads();
    if (t < 16) {
      float gv[4]; int ge[4];
      softmax_top4(sl[t], gv, ge);
#pragma unroll
      for (int i = 0; i < 16; ++i) sg[t][i] = 0.f;
      for (int j = 0; j < 4; ++j) sg[t][ge[j]] = gv[j];
    }
    __syncthreads();
    if (t < 16) {
      int ee = t; float imp = 0.f, ld = 0.f;
      for (int bb = 0; bb < 16; ++bb) {
        float g = sg[bb][ee];
        imp += g;
        if (g > 0.f) ld += 1.f;
      }
      simp[ee] = imp; sld[ee] = ld;
    }
    __syncthreads();
    if (t == 0) {
      float mi = 0.f, ml = 0.f;
      for (int i = 0; i < 16; ++i) { mi += simp[i]; ml += sld[i]; }
      mi *= (1.f / 16.f); ml *= (1.f / 16.f);
      float vi = 0.f, vl = 0.f;
      for (int i = 0; i < 16; ++i) {
        float d = simp[i] - mi; vi += d * d;
        float dl = sld[i] - ml; vl += dl * dl;
      }
      vi *= (1.f / 15.f); vl *= (1.f / 15.f);  // ddof=1
      loss_out[0] = (vi / (mi * mi + 1e-10f) + vl / (ml * ml + 1e-10f)) * 0.01f;
    }
    return;
  }

  // ---- combine block: derive this b's gates locally, then combine slab ----
  __shared__ float red[4][64];
  __shared__ float sgx[64];
  __shared__ float sl[16];
  __shared__ float g[4];
  __shared__ int e[4];
  __shared__ float was[2304];  // [co_l][ci][p] in W-native order
  {
    int hg = t >> 6, ci = t & 63;
    float s = 0.f;
#pragma unroll
    for (int hh = 0; hh < 16; ++hh)
      s += gpart[((size_t)(b * 64 + hg * 16 + hh)) * 64 + ci];
    red[hg][ci] = s;
  }
  __syncthreads();
  if (t < 64) sgx[t] = (red[0][t] + red[1][t] + red[2][t] + red[3][t]) * (1.0f / 4096.0f);
  __syncthreads();
  if (t < 16) {
    float acc = 0.f;
    for (int c = 0; c < 64; ++c) acc += sgx[c] * w_gate[c * 16 + t];
    sl[t] = acc;
  }
  __syncthreads();
  if (t == 0) {
    float gv[4]; int ge[4];
    softmax_top4(sl, gv, ge);
#pragma unroll
    for (int j = 0; j < 4; ++j) { g[j] = gv[j]; e[j] = ge[j]; }
  }
  __syncthreads();
  float g0 = g[0], g1 = g[1], g2 = g[2], g3 = g[3];
  int e0 = e[0], e1 = e[1], e2 = e[2], e3 = e[3];
  if (cog == 0 && t < 64)
    bc[b * 64 + t] = g0 * bias[e0 * 64 + t] + g1 * bias[e1 * 64 + t] +
                     g2 * bias[e2 * 64 + t] + g3 * bias[e3 * 64 + t];
  const float* b0 = W + e0 * 36864 + cog * 2304;
  const float* b1 = W + e1 * 36864 + cog * 2304;
  const float* b2 = W + e2 * 36864 + cog * 2304;
  const float* b3 = W + e3 * 36864 + cog * 2304;
  float acc[9];
#pragma unroll
  for (int j = 0; j < 9; ++j) {
    int o = t + j * 256;  // coalesced
    acc[j] = g0 * b0[o] + g1 * b1[o] + g2 * b2[o] + g3 * b3[o];
  }
#pragma unroll
  for (int j = 0; j < 9; ++j) was[t + j * 256] = acc[j];
  __syncthreads();
  for (int v = t; v < 288; v += 256) {
    int co_l = v & 3, gg = (v >> 2) & 7, p = v >> 5;
    bf16x8 ov;
#pragma unroll
    for (int j = 0; j < 8; ++j)
      ov[j] = (short)f2bf(was[co_l * 576 + (gg * 8 + j) * 9 + p]);
    *(bf16x8*)(wc + (size_t)b * 36864 + ((p * 8 + gg) * 64 + cog * 4 + co_l) * 8) = ov;
  }
}

// ---- Kernel D: conv via 9 shifted K=64 bf16 MFMA GEMMs --------------------
// grid (16 row-tiles, 16 b) = 256 blocks; 512 threads = 8 waves;
// wc[b] slab (72 KB = 4608 x 16B vectors) staged in LDS (9 iters x 512 thr);
// wave = (row, col-half): 64co x 32px, 4x2 MFMA tiles.
__global__ __launch_bounds__(512, 2) void conv_mfma(const unsigned short* __restrict__ xt,
                                                    const unsigned short* __restrict__ wc,
                                                    const float* __restrict__ bc,
                                                    float* __restrict__ y) {
  __shared__ __align__(16) unsigned short wcs[36864];  // 72 KB
  int rt = blockIdx.x;  // 0..15
  int b = blockIdx.y;   // 0..15
  int tid = threadIdx.x;
  const unsigned short* wcb = wc + (size_t)b * 36864;
  // stage combined-weight slab: 4608 x 16B, coalesced, 9 per thread
#pragma unroll
  for (int i = 0; i < 9; ++i)
    ((bf16x8*)wcs)[tid + i * 512] = ((const bf16x8*)wcb)[tid + i * 512];
  __syncthreads();

  int wv = tid >> 6, L = tid & 63;
  int lane15 = L & 15, quad = L >> 4;
  int row = rt * 4 + (wv >> 1);
  int colbase = (wv & 1) * 32;
  const unsigned short* xtb = xt + ((size_t)b << 18);  // 64h*8g*64w*8
  f32x4 acc[4][2];
#pragma unroll
  for (int mt = 0; mt < 4; ++mt)
#pragma unroll
    for (int nt = 0; nt < 2; ++nt) acc[mt][nt] = (f32x4){0.f, 0.f, 0.f, 0.f};
  const bf16x8 zero = {0, 0, 0, 0, 0, 0, 0, 0};
#pragma unroll
  for (int p = 0; p < 9; ++p) {
    int dr = p / 3, dc = p % 3;
    int h = row + dr - 1;
    bool hok = (unsigned)h < 64u;
#pragma unroll
    for (int ck = 0; ck < 2; ++ck) {
      int g = ck * 4 + quad;
      bf16x8 bfr[2];
#pragma unroll
      for (int nt = 0; nt < 2; ++nt) {
        int w = colbase + nt * 16 + lane15 + dc - 1;
        bf16x8 v = zero;
        if (hok && (unsigned)w < 64u)
          v = *(const bf16x8*)(xtb + (((h << 3) + g) << 9) + (w << 3));
        bfr[nt] = v;
      }
      bf16x8 afr[4];
#pragma unroll
      for (int mt = 0; mt < 4; ++mt)
        afr[mt] = *(const bf16x8*)(wcs + ((((p << 3) + g) << 6) + mt * 16 + lane15) * 8);
#pragma unroll
      for (int mt = 0; mt < 4; ++mt)
#pragma unroll
        for (int nt = 0; nt < 2; ++nt)
          acc[mt][nt] = __builtin_amdgcn_mfma_f32_16x16x32_bf16(afr[mt], bfr[nt], acc[mt][nt], 0, 0, 0);
    }
  }
#pragma unroll
  for (int mt = 0; mt < 4; ++mt) {
#pragma unroll
    for (int r = 0; r < 4; ++r) {
      int co = mt * 16 + quad * 4 + r;
      float bv = bc[(b << 6) + co];
#pragma unroll
      for (int nt = 0; nt < 2; ++nt) {
        int w = colbase + nt * 16 + lane15;
        y[(((size_t)(b << 6) + co) << 12) + (row << 6) + w] = acc[mt][nt][r] + bv;
      }
    }
  }
}

// ---------------------------------------------------------------------------
extern "C" void kernel_launch(void* const* d_in, const int* in_sizes, int n_in,
                              void* d_out, int out_size, void* d_ws, size_t ws_size,
                              hipStream_t stream) {
  const float* x = (const float*)d_in[0];       // (16,64,64,64)
  const float* w_gate = (const float*)d_in[1];  // (64,16)
  const float* W = (const float*)d_in[3];       // (16,64,64,3,3)
  const float* bias = (const float*)d_in[4];    // (16,64)
  float* out = (float*)d_out;                   // y (4194304) ++ loss (1)
  float* ws = (float*)d_ws;

  float* gpart = ws;                                     // [0, 65536) f
  float* bc = ws + 65536;                                // [65536, 66560) f
  unsigned short* wc = (unsigned short*)(ws + 66560);    // 589824 bf16
  unsigned short* xt = (unsigned short*)(ws + 361472);   // 4194304 bf16

  transpose_kernel<<<1024, 256, 0, stream>>>(x, xt, gpart);
  {
    dim3 grid(17, 16);
    combine_gate_kernel<<<grid, 256, 0, stream>>>(gpart, w_gate, W, bias, wc, bc,
                                                  out + 4194304);
  }
  {
    dim3 grid(16, 16);
    conv_mfma<<<grid, 512, 0, stream>>>(xt, wc, bc, out);
  }
}